// Round 14
// baseline (3313.562 us; speedup 1.0000x reference)
//
#include <hip/hip_runtime.h>
#include <hip/hip_bf16.h>

typedef __attribute__((ext_vector_type(8)))  short          bf16x8;
typedef __attribute__((ext_vector_type(4)))  float          f32x4;
typedef __attribute__((ext_vector_type(8)))  unsigned short us8;

__device__ __forceinline__ unsigned short f2b(float f) {
  union { __hip_bfloat16 h; unsigned short u; } v;
  v.h = __float2bfloat16(f);
  return v.u;
}
__device__ __forceinline__ float b2f(unsigned short u) {
  union { unsigned u; float f; } v; v.u = ((unsigned)u) << 16; return v.f;
}
__device__ __forceinline__ float sigf(float x) {
  return __builtin_amdgcn_rcpf(1.f + __expf(-x));
}
__device__ __forceinline__ float tanhf_(float x) {
  return 2.f * __builtin_amdgcn_rcpf(1.f + __expf(-2.f * x)) - 1.f;
}

// ---------- merged conversion kernel (R12 verbatim, verified) ----------
__global__ __launch_bounds__(256) void conv_all(const float* __restrict__ embeds,
                                                const float* __restrict__ Wx,
                                                const float* __restrict__ Wh,
                                                unsigned short* __restrict__ ebf,
                                                unsigned short* __restrict__ wxf,
                                                unsigned short* __restrict__ whp) {
  const int b = blockIdx.x;
  if (b < 32768) {
    const int id = b * 256 + threadIdx.x;          // 8,388,608 units
    const int l  = id & 63;
    const int kt = (id >> 6) & 31;
    const int rt = id >> 11;
    const size_t src = ((size_t)(rt * 16 + (l & 15))) * 1024 + kt * 32 + (l >> 4) * 8;
    const float4 v0 = *(const float4*)(embeds + src);
    const float4 v1 = *(const float4*)(embeds + src + 4);
    us8 o;
    o[0]=f2b(v0.x); o[1]=f2b(v0.y); o[2]=f2b(v0.z); o[3]=f2b(v0.w);
    o[4]=f2b(v1.x); o[5]=f2b(v1.y); o[6]=f2b(v1.z); o[7]=f2b(v1.w);
    *(us8*)(ebf + (size_t)id * 8) = o;
  } else if (b < 34816) {
    const int id = (b - 32768) * 256 + threadIdx.x; // 524288 units
    const int l  = id & 63;
    const int kt = (id >> 6) & 31;
    const int c  = id >> 11;
    const int col = c * 16 + (l & 15);
    const int k0 = kt * 32 + (l >> 4) * 8;
    us8 o;
    #pragma unroll
    for (int j = 0; j < 8; ++j) o[j] = f2b(Wx[(size_t)(k0 + j) * 4096 + col]);
    *(us8*)(wxf + (size_t)id * 8) = o;
  } else {
    const int id = (b - 34816) * 256 + threadIdx.x; // 524288 units
    const int l  = id & 63;
    const int kt = (id >> 6) & 7;
    const int nt = (id >> 9) & 7;
    const int kq = (id >> 12) & 3;
    const int n  = id >> 14;
    const int zi = nt * 16 + (l & 15);
    const int col = (zi >> 5) * 1024 + n * 32 + (zi & 31);
    const int k0 = kq * 256 + kt * 32 + (l >> 4) * 8;
    us8 o;
    #pragma unroll
    for (int j = 0; j < 8; ++j) o[j] = f2b(Wh[(size_t)(k0 + j) * 4096 + col]);
    *(us8*)(whp + (size_t)id * 8) = o;
  }
}

// ---------- register-only fragment-packed xproj GEMM (R12-verified data path)
// + XCD-grouped tiling: block b -> xcd=b&7 (round-robin heuristic, perf-only),
// all 4 waves share one ct (B-frags L2-resident, 4x reuse), 4 cts per XCD
// (1MB B working set per L2). Bijective: (ct, rt) covered exactly once.
__global__ __launch_bounds__(256, 2) void gemm_xproj_reg(
    const unsigned short* __restrict__ ebf,
    const unsigned short* __restrict__ wxf,
    const float* __restrict__ bias,
    unsigned short* __restrict__ xp) {
  const int lane = threadIdx.x & 63;
  const int wv = threadIdx.x >> 6;
  const int xcd = blockIdx.x & 7;
  const int local = blockIdx.x >> 3;           // 0..1023
  const int ct = xcd * 4 + (local & 3);        // 128-col tile (0..31)
  const int rt = (local >> 2) * 4 + wv;        // 64-row tile (0..1023)

  float bvf[8];
  #pragma unroll
  for (int nt = 0; nt < 8; ++nt) bvf[nt] = bias[ct * 128 + nt * 16 + (lane & 15)];

  f32x4 acc[4][8];
  #pragma unroll
  for (int a = 0; a < 4; ++a)
    #pragma unroll
    for (int nt = 0; nt < 8; ++nt) acc[a][nt] = f32x4{0.f,0.f,0.f,0.f};

  for (int kt = 0; kt < 32; ++kt) {
    bf16x8 af[4], bfr[8];
    #pragma unroll
    for (int a = 0; a < 4; ++a)
      af[a] = *(const bf16x8*)(ebf + (size_t)((4 * rt + a) * 32 + kt) * 512 + lane * 8);
    #pragma unroll
    for (int nt = 0; nt < 8; ++nt)
      bfr[nt] = *(const bf16x8*)(wxf + (size_t)((ct * 8 + nt) * 32 + kt) * 512 + lane * 8);
    #pragma unroll
    for (int a = 0; a < 4; ++a)
      #pragma unroll
      for (int nt = 0; nt < 8; ++nt)
        acc[a][nt] = __builtin_amdgcn_mfma_f32_16x16x32_bf16(af[a], bfr[nt], acc[a][nt], 0, 0, 0);
  }

  // epilogue: C/D col=lane&15, row=(lane>>4)*4+rr; bias folded HERE (only here)
  #pragma unroll
  for (int a = 0; a < 4; ++a) {
    const int row0 = rt * 64 + a * 16 + (lane >> 4) * 4;
    #pragma unroll
    for (int nt = 0; nt < 8; ++nt) {
      const int col = ct * 128 + nt * 16 + (lane & 15);
      #pragma unroll
      for (int rr = 0; rr < 4; ++rr)
        xp[(size_t)(row0 + rr) * 4096 + col] = f2b(acc[a][nt][rr] + bvf[nt]);
    }
  }
}

// ---------- persistent recurrence kernel (R12 + per-wave flags, no barrier #2)
// flags[cons 256][prod 32][wave 4] u32 (128KB). Producer wave kq: barrier#1 ->
// reduce -> act -> h-store -> OWN vmcnt drain -> broadcast its (prod=n, wave=kq)
// flag to all 32 consumers. Consumer wave kq polls its 32 (prod x wave) flags
// (contiguous 128B: slot kq*32+lane). Safety: h-stores sit after __syncthreads
// barrier#1, which aggregates all 4 waves' polls => all 32 blocks x 4 waves
// certified done reading buf before any overwrite. zpart parity-double-buffered
// (dump t+1 never touches slice being reduced at t; t+2 reuse covered by the
// producer-flag chain: flag(t+1) is published only after reduce(t)).
__global__ __launch_bounds__(256, 1) void lstm_recur(
    const unsigned short* __restrict__ xproj,  // [512*128][4096] bf16, bias folded
    const unsigned short* __restrict__ Wp,     // packed fragments
    unsigned short* __restrict__ hbuf,         // [2][128][1024] bf16 row-major
    float* __restrict__ out,                   // [512][128][1024]
    unsigned* __restrict__ flags) {            // [256][32][4] per-wave mailboxes
  __shared__ float zpart[2][5][16][132];       // parity x kq(5th pad: 1 block/CU)
  const int tid = threadIdx.x;
  const int lane = tid & 63;
  const int kq = tid >> 6;                     // wave = K-quarter
  const int m = blockIdx.x >> 5;               // group / 16-row batch stripe
  const int n = blockIdx.x & 31;               // 128-z-col slot

  // W_h fragments -> VGPRs (64 x bf16x8, held whole kernel)
  bf16x8 wf[64];
  {
    const unsigned short* wb = Wp + ((size_t)(n * 4 + kq) * 64) * 512 + lane * 8;
    #pragma unroll
    for (int f = 0; f < 64; ++f) wf[f] = *(const bf16x8*)(wb + f * 512);
  }

  const int r    = tid >> 4;                   // row within stripe (0..15)
  const int hg   = tid & 15;                   // h-col pair group
  const int hc0  = n * 32 + hg * 2;            // h col (0..1023)
  const int grow = m * 16 + r;                 // global batch row

  float cr0 = 0.f, cr1 = 0.f;
  const size_t xbase = (size_t)grow * 4096 + hc0;
  // broadcast: lane l (<32) stores my (prod=n, wave=kq) flag to consumer l
  unsigned* bcast = flags + ((m * 32 + (lane & 31)) * 128) + n * 4 + kq;
  // poll: wave kq's 32 deps are contiguous slots [kq*32, kq*32+32)
  const unsigned* myf = flags + ((size_t)(m * 32 + n) * 128) + kq * 32 + (lane & 31);

  // prologue: xproj loads for step 0
  unsigned xu0, xu1, xu2, xu3;
  {
    const unsigned short* xpp = xproj + xbase;
    asm volatile("global_load_dword %0, %1, off" : "=v"(xu0) : "v"(xpp));
    asm volatile("global_load_dword %0, %1, off" : "=v"(xu1) : "v"(xpp + 1024));
    asm volatile("global_load_dword %0, %1, off" : "=v"(xu2) : "v"(xpp + 2048));
    asm volatile("global_load_dword %0, %1, off" : "=v"(xu3) : "v"(xpp + 3072));
  }

  // A-frag addr: row (lane&15) of stripe, k = kq*256 + (lane>>4)*8 (+kt*32 imm)
  const size_t aoff = ((size_t)(m * 16 + (lane & 15))) * 1024 + kq * 256 + (lane >> 4) * 8;

  for (int t = 0; t < 511; ++t) {
    const unsigned short* ab = hbuf + (t & 1) * 131072 + aoff;
    const int par = t & 1;

    bf16x8 av0, av1, av2, av3, av4, av5, av6, av7;
    __builtin_amdgcn_sched_barrier(0);
    asm volatile("global_load_dwordx4 %0, %1, off sc0 sc1"            : "=v"(av0) : "v"(ab));
    asm volatile("global_load_dwordx4 %0, %1, off offset:64 sc0 sc1"  : "=v"(av1) : "v"(ab));
    asm volatile("global_load_dwordx4 %0, %1, off offset:128 sc0 sc1" : "=v"(av2) : "v"(ab));
    asm volatile("global_load_dwordx4 %0, %1, off offset:192 sc0 sc1" : "=v"(av3) : "v"(ab));
    asm volatile("global_load_dwordx4 %0, %1, off offset:256 sc0 sc1" : "=v"(av4) : "v"(ab));
    asm volatile("global_load_dwordx4 %0, %1, off offset:320 sc0 sc1" : "=v"(av5) : "v"(ab));
    asm volatile("global_load_dwordx4 %0, %1, off offset:384 sc0 sc1" : "=v"(av6) : "v"(ab));
    asm volatile("global_load_dwordx4 %0, %1, off offset:448 sc0 sc1" : "=v"(av7) : "v"(ab));
    asm volatile("s_waitcnt vmcnt(0)" ::: "memory");
    __builtin_amdgcn_sched_barrier(0);

    // MFMA: 8 n-tiles x 8 k-tiles of 16x16x32; acc reuse distance 8
    f32x4 ac0 = {0.f,0.f,0.f,0.f}, ac1 = {0.f,0.f,0.f,0.f};
    f32x4 ac2 = {0.f,0.f,0.f,0.f}, ac3 = {0.f,0.f,0.f,0.f};
    f32x4 ac4 = {0.f,0.f,0.f,0.f}, ac5 = {0.f,0.f,0.f,0.f};
    f32x4 ac6 = {0.f,0.f,0.f,0.f}, ac7 = {0.f,0.f,0.f,0.f};
#define MF_STEP(AV, KT) \
    ac0 = __builtin_amdgcn_mfma_f32_16x16x32_bf16(AV, wf[ 0 + KT], ac0, 0, 0, 0); \
    ac1 = __builtin_amdgcn_mfma_f32_16x16x32_bf16(AV, wf[ 8 + KT], ac1, 0, 0, 0); \
    ac2 = __builtin_amdgcn_mfma_f32_16x16x32_bf16(AV, wf[16 + KT], ac2, 0, 0, 0); \
    ac3 = __builtin_amdgcn_mfma_f32_16x16x32_bf16(AV, wf[24 + KT], ac3, 0, 0, 0); \
    ac4 = __builtin_amdgcn_mfma_f32_16x16x32_bf16(AV, wf[32 + KT], ac4, 0, 0, 0); \
    ac5 = __builtin_amdgcn_mfma_f32_16x16x32_bf16(AV, wf[40 + KT], ac5, 0, 0, 0); \
    ac6 = __builtin_amdgcn_mfma_f32_16x16x32_bf16(AV, wf[48 + KT], ac6, 0, 0, 0); \
    ac7 = __builtin_amdgcn_mfma_f32_16x16x32_bf16(AV, wf[56 + KT], ac7, 0, 0, 0);
    MF_STEP(av0, 0) MF_STEP(av1, 1) MF_STEP(av2, 2) MF_STEP(av3, 3)
    MF_STEP(av4, 4) MF_STEP(av5, 5) MF_STEP(av6, 6) MF_STEP(av7, 7)
#undef MF_STEP

    // dump partials into parity slice: 16x16 C/D: col=lane&15, row=(lane>>4)*4+reg
    {
      const int crow = (lane >> 4) * 4, ccol = lane & 15;
#define DUMP(NT, AC) \
      zpart[par][kq][crow + 0][NT * 16 + ccol] = AC[0]; \
      zpart[par][kq][crow + 1][NT * 16 + ccol] = AC[1]; \
      zpart[par][kq][crow + 2][NT * 16 + ccol] = AC[2]; \
      zpart[par][kq][crow + 3][NT * 16 + ccol] = AC[3];
      DUMP(0, ac0) DUMP(1, ac1) DUMP(2, ac2) DUMP(3, ac3)
      DUMP(4, ac4) DUMP(5, ac5) DUMP(6, ac6) DUMP(7, ac7)
#undef DUMP
    }
    __syncthreads();   // barrier #1 (the only block barrier per step)

    // cross-wave K reduction: local z-col = g*32 + (hg*2+j); bias already in xp
    float zc[4][2];
    #pragma unroll
    for (int g = 0; g < 4; ++g)
      #pragma unroll
      for (int j = 0; j < 2; ++j) {
        const int col = g * 32 + hg * 2 + j;
        zc[g][j] = (zpart[par][0][r][col] + zpart[par][1][r][col])
                 + (zpart[par][2][r][col] + zpart[par][3][r][col]);
      }

    float hv0, hv1;
    {
      const float zg = zc[0][0] + b2f((unsigned short)(xu0 & 0xffffu));
      const float zi = zc[1][0] + b2f((unsigned short)(xu1 & 0xffffu));
      const float zf = zc[2][0] + b2f((unsigned short)(xu2 & 0xffffu));
      const float zo = zc[3][0] + b2f((unsigned short)(xu3 & 0xffffu));
      cr0 = tanhf_(zg) * sigf(zi) + cr0 * sigf(zf);
      hv0 = tanhf_(cr0) * sigf(zo);
    }
    {
      const float zg = zc[0][1] + b2f((unsigned short)(xu0 >> 16));
      const float zi = zc[1][1] + b2f((unsigned short)(xu1 >> 16));
      const float zf = zc[2][1] + b2f((unsigned short)(xu2 >> 16));
      const float zo = zc[3][1] + b2f((unsigned short)(xu3 >> 16));
      cr1 = tanhf_(zg) * sigf(zi) + cr1 * sigf(zf);
      hv1 = tanhf_(cr1) * sigf(zo);
    }

    if (t < 510) {
      // h store -> OWN drain -> per-wave flag broadcast (no block barrier)
      const unsigned hp = (unsigned)f2b(hv0) | ((unsigned)f2b(hv1) << 16);
      unsigned short* hd = hbuf + ((t & 1) ^ 1) * 131072 + (size_t)grow * 1024 + hc0;
      asm volatile("global_store_dword %0, %1, off sc0 sc1" :: "v"(hd), "v"(hp) : "memory");
      asm volatile("s_waitcnt vmcnt(0)" ::: "memory");
      if (lane < 32) {
        const unsigned g1 = (unsigned)(t + 1);
        asm volatile("global_store_dword %0, %1, off sc0 sc1" :: "v"(bcast), "v"(g1) : "memory");
      }
    }

    // out[t+1] = h after step t (out[0]=0 via memset); rides through poll phase
    float2 ho; ho.x = hv0; ho.y = hv1;
    *(float2*)(out + ((size_t)(t + 1) * 128 + grow) * 1024 + hc0) = ho;

    if (t < 510) {
      // prefetch next xproj (latency hides under the poll)
      const unsigned short* xpp = xproj + (size_t)(t + 1) * 524288 + xbase;
      asm volatile("global_load_dword %0, %1, off" : "=v"(xu0) : "v"(xpp));
      asm volatile("global_load_dword %0, %1, off" : "=v"(xu1) : "v"(xpp + 1024));
      asm volatile("global_load_dword %0, %1, off" : "=v"(xu2) : "v"(xpp + 2048));
      asm volatile("global_load_dword %0, %1, off" : "=v"(xu3) : "v"(xpp + 3072));
      // per-wave poll: 32 contiguous (prod x wave) flags; lane l watches slot l
      unsigned v;
      do {
        asm volatile("global_load_dword %0, %1, off sc0 sc1" : "=v"(v) : "v"(myf));
        asm volatile("s_waitcnt vmcnt(0)" ::: "memory");
      } while (__any((int)v <= t));
    }
  }
}

extern "C" void kernel_launch(void* const* d_in, const int* in_sizes, int n_in,
                              void* d_out, int out_size, void* d_ws, size_t ws_size,
                              hipStream_t stream) {
  (void)in_sizes; (void)n_in; (void)out_size; (void)ws_size;
  const float* embeds = (const float*)d_in[0];
  const float* Wx     = (const float*)d_in[1];
  const float* Wh     = (const float*)d_in[2];
  const float* bias   = (const float*)d_in[3];
  float* out = (float*)d_out;

  char* w = (char*)d_ws;
  unsigned short* ebf = (unsigned short*)(w);                 // 134,217,728 B
  unsigned short* wxf = (unsigned short*)(w + 134217728);     //   8,388,608 B
  unsigned short* whp = (unsigned short*)(w + 142606336);     //   8,388,608 B
  unsigned short* xpb = (unsigned short*)(w + 150994944);     // 536,870,912 B
  unsigned short* hb  = (unsigned short*)(w + 687865856);     //     524,288 B
  unsigned*       fl  = (unsigned*)(w + 688390144);           //     131,072 B

  hipMemsetAsync(d_out, 0, (size_t)128 * 1024 * sizeof(float), stream);
  hipMemsetAsync(hb, 0, 524288, stream);
  hipMemsetAsync(fl, 0, 131072, stream);

  conv_all      <<<36864, 256, 0, stream>>>(embeds, Wx, Wh, ebf, wxf, whp);
  gemm_xproj_reg<<<8192,  256, 0, stream>>>(ebf, wxf, bias, xpb);
  lstm_recur    <<<256,   256, 0, stream>>>(xpb, whp, hb, out, fl);
}

// Round 15
// 2550.966 us; speedup vs baseline: 1.2989x; 1.2989x over previous
//
#include <hip/hip_runtime.h>
#include <hip/hip_bf16.h>

typedef __attribute__((ext_vector_type(8)))  short          bf16x8;
typedef __attribute__((ext_vector_type(4)))  float          f32x4;
typedef __attribute__((ext_vector_type(8)))  unsigned short us8;

__device__ __forceinline__ unsigned short f2b(float f) {
  union { __hip_bfloat16 h; unsigned short u; } v;
  v.h = __float2bfloat16(f);
  return v.u;
}
__device__ __forceinline__ float b2f(unsigned short u) {
  union { unsigned u; float f; } v; v.u = ((unsigned)u) << 16; return v.f;
}
__device__ __forceinline__ float sigf(float x) {
  return __builtin_amdgcn_rcpf(1.f + __expf(-x));
}
__device__ __forceinline__ float tanhf_(float x) {
  return 2.f * __builtin_amdgcn_rcpf(1.f + __expf(-2.f * x)) - 1.f;
}

// ---------- merged conversion kernel (R10-verified bodies) ----------
// [0,32768): embeds f32 -> eb bf16 row-major [65536][1024]
// [32768,33792): W_x -> WxT bf16 row-major [4096][1024] (transpose)
// [33792,35840): W_h -> whp packed B fragments (verified R6 layout)
__global__ __launch_bounds__(256) void conv_all(const float* __restrict__ embeds,
                                                const float* __restrict__ Wx,
                                                const float* __restrict__ Wh,
                                                unsigned short* __restrict__ eb,
                                                unsigned short* __restrict__ WxT,
                                                unsigned short* __restrict__ whp) {
  __shared__ float tile[64][65];
  const int b = blockIdx.x;
  if (b < 32768) {
    const size_t i = ((size_t)b * 256 + threadIdx.x) * 8;
    const float4 v0 = *(const float4*)(embeds + i);
    const float4 v1 = *(const float4*)(embeds + i + 4);
    us8 o;
    o[0]=f2b(v0.x); o[1]=f2b(v0.y); o[2]=f2b(v0.z); o[3]=f2b(v0.w);
    o[4]=f2b(v1.x); o[5]=f2b(v1.y); o[6]=f2b(v1.z); o[7]=f2b(v1.w);
    *(us8*)(eb + i) = o;
  } else if (b < 33792) {
    const int b2 = b - 32768;
    const int bx = b2 & 63;
    const int by = b2 >> 6;
    const int tc = threadIdx.x & 63, tr = threadIdx.x >> 6;
    #pragma unroll
    for (int i = 0; i < 16; ++i) {
      const int r = i * 4 + tr;
      tile[r][tc] = Wx[(size_t)(by * 64 + r) * 4096 + bx * 64 + tc];
    }
    __syncthreads();
    #pragma unroll
    for (int i = 0; i < 16; ++i) {
      const int c = i * 4 + tr;
      WxT[(size_t)(bx * 64 + c) * 1024 + by * 64 + tc] = f2b(tile[tc][c]);
    }
  } else {
    const int id = (b - 33792) * 256 + threadIdx.x;  // 524288 units
    const int l  = id & 63;
    const int kt = (id >> 6) & 7;
    const int nt = (id >> 9) & 7;
    const int kq = (id >> 12) & 3;
    const int n  = id >> 14;
    const int zi = nt * 16 + (l & 15);
    const int col = (zi >> 5) * 1024 + n * 32 + (zi & 31);
    const int k0 = kq * 256 + kt * 32 + (l >> 4) * 8;
    us8 o;
    #pragma unroll
    for (int j = 0; j < 8; ++j) o[j] = f2b(Wh[(size_t)(k0 + j) * 4096 + col]);
    *(us8*)(whp + (size_t)id * 8) = o;
  }
}

// ---------- 8-phase-style 256x256 xproj GEMM ----------
// BM=BN=256, BK=64, 512 thr (8 waves: wr=wv>>2, wc=wv&3). LDS 128KB:
// lds[dbuf][A/B][half 128rows][16KB], content XOR-swizzled (phys kb =
// logical kb ^ ((row&7)<<4)) via inverse-swizzled GLOBAL source + linear
// global_load_lds dest (rule #21). 4 phases/K-tile: {A-frag ds_reads |
// staging (front-loaded p0/p1) | barrier | lgkmcnt(0) | setprio(1) 16 MFMA
// setprio(0) | barrier}; vmcnt(0) once per K-tile at p3 (loads issued 2-3
// phases earlier -> drain cheap). XCD-bijective block swizzle (4096%8==0).
__global__ __launch_bounds__(512, 1) void gemm_xproj_8p(
    const unsigned short* __restrict__ A,    // eb row-major [65536][1024]
    const unsigned short* __restrict__ B,    // WxT row-major [4096][1024]
    const float* __restrict__ bias,
    unsigned short* __restrict__ C) {        // xp [65536][4096]
  __shared__ unsigned short lds[2][2][2][8192];
  const int tid = threadIdx.x;
  const int lane = tid & 63;
  const int wv = tid >> 6;
  const int wr = wv >> 2;
  const int wc = wv & 3;
  const int sid = (blockIdx.x & 7) * 512 + (blockIdx.x >> 3);
  const int bm = sid >> 4;                   // 0..255 (M tile)
  const int bn = sid & 15;                   // 0..15  (N tile)
  const int l15 = lane & 15;

  // read-side swizzled K offsets (elems): (ks*64 + (lane>>4)*16) ^ ((lane&7)<<4), /2
  const int kx0e = (((lane >> 4) * 16) ^ ((lane & 7) << 4)) >> 1;
  const int kx1e = ((64 + (lane >> 4) * 16) ^ ((lane & 7) << 4)) >> 1;

  // staging per-lane source geometry: chunk c = wv*2+j; row = c*8+(lane>>3);
  // src K elems = 8*((lane&7)^(lane>>3))  (inverse swizzle)
  const int srow0 = wv * 16 + (lane >> 3);
  const int srow1 = wv * 16 + 8 + (lane >> 3);
  const int skoff = 8 * ((lane & 7) ^ (lane >> 3));

#define STAGE(D, MAT, HALF, GSRC, GROW0, KT2) { \
    const unsigned short* s0_ = (GSRC) + (size_t)((GROW0) + srow0) * 1024 + (KT2) * 64 + skoff; \
    const unsigned short* s1_ = (GSRC) + (size_t)((GROW0) + srow1) * 1024 + (KT2) * 64 + skoff; \
    __builtin_amdgcn_global_load_lds( \
        (const __attribute__((address_space(1))) unsigned short*)s0_, \
        (__attribute__((address_space(3))) unsigned short*)(&lds[D][MAT][HALF][(wv * 2) * 512]), 16, 0, 0); \
    __builtin_amdgcn_global_load_lds( \
        (const __attribute__((address_space(1))) unsigned short*)s1_, \
        (__attribute__((address_space(3))) unsigned short*)(&lds[D][MAT][HALF][(wv * 2 + 1) * 512]), 16, 0, 0); }

  // bias hoist (per nf)
  float bvf[4];
  #pragma unroll
  for (int nf = 0; nf < 4; ++nf)
    bvf[nf] = bias[bn * 256 + wc * 64 + nf * 16 + l15];

  f32x4 acc[8][4];
  #pragma unroll
  for (int mf = 0; mf < 8; ++mf)
    #pragma unroll
    for (int nf = 0; nf < 4; ++nf) acc[mf][nf] = f32x4{0.f, 0.f, 0.f, 0.f};

  // prologue: stage K-tile 0 (all 4 halves) into dbuf 0
  STAGE(0, 0, 0, A, bm * 256, 0)
  STAGE(0, 0, 1, A, bm * 256 + 128, 0)
  STAGE(0, 1, 0, B, bn * 256, 0)
  STAGE(0, 1, 1, B, bn * 256 + 128, 0)
  asm volatile("s_waitcnt vmcnt(0)" ::: "memory");
  __builtin_amdgcn_s_barrier();

  for (int kt = 0; kt < 16; ++kt) {
    const int cur = kt & 1;
    // B-frags for this K-tile (held across all 4 phases)
    bf16x8 bv[4][2];
    #pragma unroll
    for (int nf = 0; nf < 4; ++nf) {
      const int brow = (wc & 1) * 64 + nf * 16 + l15;
      bv[nf][0] = *(const bf16x8*)(&lds[cur][1][wc >> 1][brow * 64 + kx0e]);
      bv[nf][1] = *(const bf16x8*)(&lds[cur][1][wc >> 1][brow * 64 + kx1e]);
    }
    #pragma unroll
    for (int p = 0; p < 4; ++p) {
      bf16x8 av[2][2];
      #pragma unroll
      for (int mf2 = 0; mf2 < 2; ++mf2) {
        const int arow = (p * 2 + mf2) * 16 + l15;
        av[mf2][0] = *(const bf16x8*)(&lds[cur][0][wr][arow * 64 + kx0e]);
        av[mf2][1] = *(const bf16x8*)(&lds[cur][0][wr][arow * 64 + kx1e]);
      }
      if (kt < 15) {
        if (p == 0) {
          STAGE(cur ^ 1, 0, 0, A, bm * 256, kt + 1)
          STAGE(cur ^ 1, 0, 1, A, bm * 256 + 128, kt + 1)
        } else if (p == 1) {
          STAGE(cur ^ 1, 1, 0, B, bn * 256, kt + 1)
          STAGE(cur ^ 1, 1, 1, B, bn * 256 + 128, kt + 1)
        }
      }
      if (p == 3 && kt < 15)
        asm volatile("s_waitcnt vmcnt(0)" ::: "memory");  // staged 2-3 phases ago
      __builtin_amdgcn_sched_barrier(0);
      __builtin_amdgcn_s_barrier();
      asm volatile("s_waitcnt lgkmcnt(0)" ::: "memory");
      __builtin_amdgcn_sched_barrier(0);
      __builtin_amdgcn_s_setprio(1);
      #pragma unroll
      for (int mf2 = 0; mf2 < 2; ++mf2)
        #pragma unroll
        for (int nf = 0; nf < 4; ++nf) {
          acc[p * 2 + mf2][nf] =
              __builtin_amdgcn_mfma_f32_16x16x32_bf16(av[mf2][0], bv[nf][0], acc[p * 2 + mf2][nf], 0, 0, 0);
          acc[p * 2 + mf2][nf] =
              __builtin_amdgcn_mfma_f32_16x16x32_bf16(av[mf2][1], bv[nf][1], acc[p * 2 + mf2][nf], 0, 0, 0);
        }
      __builtin_amdgcn_s_setprio(0);
      __builtin_amdgcn_sched_barrier(0);
      __builtin_amdgcn_s_barrier();
    }
  }
#undef STAGE

  // epilogue: C/D col=lane&15, row=(lane>>4)*4+rr (R10-proven); bias folded HERE
  #pragma unroll
  for (int mf = 0; mf < 8; ++mf) {
    const int row0 = bm * 256 + wr * 128 + mf * 16 + (lane >> 4) * 4;
    #pragma unroll
    for (int nf = 0; nf < 4; ++nf) {
      const int col = bn * 256 + wc * 64 + nf * 16 + l15;
      #pragma unroll
      for (int rr = 0; rr < 4; ++rr)
        C[(size_t)(row0 + rr) * 4096 + col] = f2b(acc[mf][nf][rr] + bvf[nf]);
    }
  }
}

// ---------- persistent recurrence kernel (R12 verbatim — PASSED twice) ----------
__global__ __launch_bounds__(256, 1) void lstm_recur(
    const unsigned short* __restrict__ xproj,  // [512*128][4096] bf16, bias folded
    const unsigned short* __restrict__ Wp,     // packed fragments
    unsigned short* __restrict__ hbuf,         // [2][128][1024] bf16 row-major
    float* __restrict__ out,                   // [512][128][1024]
    unsigned* __restrict__ flags) {            // [256][32] private mailboxes
  __shared__ float zpart[10][16][132];         // [0..3] used; oversized -> 1 block/CU
  const int tid = threadIdx.x;
  const int lane = tid & 63;
  const int kq = tid >> 6;                     // wave = K-quarter
  const int m = blockIdx.x >> 5;               // group / 16-row batch stripe
  const int n = blockIdx.x & 31;               // 128-z-col slot

  bf16x8 wf[64];
  {
    const unsigned short* wb = Wp + ((size_t)(n * 4 + kq) * 64) * 512 + lane * 8;
    #pragma unroll
    for (int f = 0; f < 64; ++f) wf[f] = *(const bf16x8*)(wb + f * 512);
  }

  const int r    = tid >> 4;
  const int hg   = tid & 15;
  const int hc0  = n * 32 + hg * 2;
  const int grow = m * 16 + r;

  float cr0 = 0.f, cr1 = 0.f;
  const size_t xbase = (size_t)grow * 4096 + hc0;
  unsigned* bcast = flags + (m * 32 + (lane & 31)) * 32 + n;
  const unsigned* myf = flags + (size_t)(m * 32 + n) * 32 + kq * 8 + (lane & 7);

  unsigned xu0, xu1, xu2, xu3;
  {
    const unsigned short* xpp = xproj + xbase;
    asm volatile("global_load_dword %0, %1, off" : "=v"(xu0) : "v"(xpp));
    asm volatile("global_load_dword %0, %1, off" : "=v"(xu1) : "v"(xpp + 1024));
    asm volatile("global_load_dword %0, %1, off" : "=v"(xu2) : "v"(xpp + 2048));
    asm volatile("global_load_dword %0, %1, off" : "=v"(xu3) : "v"(xpp + 3072));
  }

  const size_t aoff = ((size_t)(m * 16 + (lane & 15))) * 1024 + kq * 256 + (lane >> 4) * 8;

  for (int t = 0; t < 511; ++t) {
    const unsigned short* ab = hbuf + (t & 1) * 131072 + aoff;

    bf16x8 av0, av1, av2, av3, av4, av5, av6, av7;
    __builtin_amdgcn_sched_barrier(0);
    asm volatile("global_load_dwordx4 %0, %1, off sc0 sc1"            : "=v"(av0) : "v"(ab));
    asm volatile("global_load_dwordx4 %0, %1, off offset:64 sc0 sc1"  : "=v"(av1) : "v"(ab));
    asm volatile("global_load_dwordx4 %0, %1, off offset:128 sc0 sc1" : "=v"(av2) : "v"(ab));
    asm volatile("global_load_dwordx4 %0, %1, off offset:192 sc0 sc1" : "=v"(av3) : "v"(ab));
    asm volatile("global_load_dwordx4 %0, %1, off offset:256 sc0 sc1" : "=v"(av4) : "v"(ab));
    asm volatile("global_load_dwordx4 %0, %1, off offset:320 sc0 sc1" : "=v"(av5) : "v"(ab));
    asm volatile("global_load_dwordx4 %0, %1, off offset:384 sc0 sc1" : "=v"(av6) : "v"(ab));
    asm volatile("global_load_dwordx4 %0, %1, off offset:448 sc0 sc1" : "=v"(av7) : "v"(ab));
    asm volatile("s_waitcnt vmcnt(0)" ::: "memory");
    __builtin_amdgcn_sched_barrier(0);

    f32x4 ac0 = {0.f,0.f,0.f,0.f}, ac1 = {0.f,0.f,0.f,0.f};
    f32x4 ac2 = {0.f,0.f,0.f,0.f}, ac3 = {0.f,0.f,0.f,0.f};
    f32x4 ac4 = {0.f,0.f,0.f,0.f}, ac5 = {0.f,0.f,0.f,0.f};
    f32x4 ac6 = {0.f,0.f,0.f,0.f}, ac7 = {0.f,0.f,0.f,0.f};
#define MF_STEP(AV, KT) \
    ac0 = __builtin_amdgcn_mfma_f32_16x16x32_bf16(AV, wf[ 0 + KT], ac0, 0, 0, 0); \
    ac1 = __builtin_amdgcn_mfma_f32_16x16x32_bf16(AV, wf[ 8 + KT], ac1, 0, 0, 0); \
    ac2 = __builtin_amdgcn_mfma_f32_16x16x32_bf16(AV, wf[16 + KT], ac2, 0, 0, 0); \
    ac3 = __builtin_amdgcn_mfma_f32_16x16x32_bf16(AV, wf[24 + KT], ac3, 0, 0, 0); \
    ac4 = __builtin_amdgcn_mfma_f32_16x16x32_bf16(AV, wf[32 + KT], ac4, 0, 0, 0); \
    ac5 = __builtin_amdgcn_mfma_f32_16x16x32_bf16(AV, wf[40 + KT], ac5, 0, 0, 0); \
    ac6 = __builtin_amdgcn_mfma_f32_16x16x32_bf16(AV, wf[48 + KT], ac6, 0, 0, 0); \
    ac7 = __builtin_amdgcn_mfma_f32_16x16x32_bf16(AV, wf[56 + KT], ac7, 0, 0, 0);
    MF_STEP(av0, 0) MF_STEP(av1, 1) MF_STEP(av2, 2) MF_STEP(av3, 3)
    MF_STEP(av4, 4) MF_STEP(av5, 5) MF_STEP(av6, 6) MF_STEP(av7, 7)
#undef MF_STEP

    {
      const int crow = (lane >> 4) * 4, ccol = lane & 15;
#define DUMP(NT, AC) \
      zpart[kq][crow + 0][NT * 16 + ccol] = AC[0]; \
      zpart[kq][crow + 1][NT * 16 + ccol] = AC[1]; \
      zpart[kq][crow + 2][NT * 16 + ccol] = AC[2]; \
      zpart[kq][crow + 3][NT * 16 + ccol] = AC[3];
      DUMP(0, ac0) DUMP(1, ac1) DUMP(2, ac2) DUMP(3, ac3)
      DUMP(4, ac4) DUMP(5, ac5) DUMP(6, ac6) DUMP(7, ac7)
#undef DUMP
    }
    __syncthreads();   // barrier #1

    float zc[4][2];
    #pragma unroll
    for (int g = 0; g < 4; ++g)
      #pragma unroll
      for (int j = 0; j < 2; ++j) {
        const int col = g * 32 + hg * 2 + j;
        zc[g][j] = (zpart[0][r][col] + zpart[1][r][col])
                 + (zpart[2][r][col] + zpart[3][r][col]);
      }

    float hv0, hv1;
    {
      const float zg = zc[0][0] + b2f((unsigned short)(xu0 & 0xffffu));
      const float zi = zc[1][0] + b2f((unsigned short)(xu1 & 0xffffu));
      const float zf = zc[2][0] + b2f((unsigned short)(xu2 & 0xffffu));
      const float zo = zc[3][0] + b2f((unsigned short)(xu3 & 0xffffu));
      cr0 = tanhf_(zg) * sigf(zi) + cr0 * sigf(zf);
      hv0 = tanhf_(cr0) * sigf(zo);
    }
    {
      const float zg = zc[0][1] + b2f((unsigned short)(xu0 >> 16));
      const float zi = zc[1][1] + b2f((unsigned short)(xu1 >> 16));
      const float zf = zc[2][1] + b2f((unsigned short)(xu2 >> 16));
      const float zo = zc[3][1] + b2f((unsigned short)(xu3 >> 16));
      cr1 = tanhf_(zg) * sigf(zi) + cr1 * sigf(zf);
      hv1 = tanhf_(cr1) * sigf(zo);
    }

    if (t < 510) {
      const unsigned hp = (unsigned)f2b(hv0) | ((unsigned)f2b(hv1) << 16);
      unsigned short* hd = hbuf + ((t & 1) ^ 1) * 131072 + (size_t)grow * 1024 + hc0;
      asm volatile("global_store_dword %0, %1, off sc0 sc1" :: "v"(hd), "v"(hp) : "memory");
      asm volatile("s_waitcnt vmcnt(0)" ::: "memory");
      __syncthreads();   // barrier #2
      if (kq == 0 && lane < 32) {
        const unsigned g1 = (unsigned)(t + 1);
        asm volatile("global_store_dword %0, %1, off sc0 sc1" :: "v"(bcast), "v"(g1) : "memory");
      }
    }

    float2 ho; ho.x = hv0; ho.y = hv1;
    *(float2*)(out + ((size_t)(t + 1) * 128 + grow) * 1024 + hc0) = ho;

    if (t < 510) {
      const unsigned short* xpp = xproj + (size_t)(t + 1) * 524288 + xbase;
      asm volatile("global_load_dword %0, %1, off" : "=v"(xu0) : "v"(xpp));
      asm volatile("global_load_dword %0, %1, off" : "=v"(xu1) : "v"(xpp + 1024));
      asm volatile("global_load_dword %0, %1, off" : "=v"(xu2) : "v"(xpp + 2048));
      asm volatile("global_load_dword %0, %1, off" : "=v"(xu3) : "v"(xpp + 3072));
      unsigned v;
      do {
        asm volatile("global_load_dword %0, %1, off sc0 sc1" : "=v"(v) : "v"(myf));
        asm volatile("s_waitcnt vmcnt(0)" ::: "memory");
      } while (__any((int)v <= t));
    }
  }
}

extern "C" void kernel_launch(void* const* d_in, const int* in_sizes, int n_in,
                              void* d_out, int out_size, void* d_ws, size_t ws_size,
                              hipStream_t stream) {
  (void)in_sizes; (void)n_in; (void)out_size; (void)ws_size;
  const float* embeds = (const float*)d_in[0];
  const float* Wx     = (const float*)d_in[1];
  const float* Wh     = (const float*)d_in[2];
  const float* bias   = (const float*)d_in[3];
  float* out = (float*)d_out;

  char* w = (char*)d_ws;
  unsigned short* eb  = (unsigned short*)(w);                 // 134,217,728 B
  unsigned short* WxT = (unsigned short*)(w + 134217728);     //   8,388,608 B
  unsigned short* whp = (unsigned short*)(w + 142606336);     //   8,388,608 B
  unsigned short* xpb = (unsigned short*)(w + 150994944);     // 536,870,912 B
  unsigned short* hb  = (unsigned short*)(w + 687865856);     //     524,288 B
  unsigned*       fl  = (unsigned*)(w + 688390144);           //      32,768 B

  hipMemsetAsync(d_out, 0, (size_t)128 * 1024 * sizeof(float), stream);
  hipMemsetAsync(hb, 0, 524288, stream);
  hipMemsetAsync(fl, 0, 32768, stream);

  conv_all     <<<35840, 256, 0, stream>>>(embeds, Wx, Wh, eb, WxT, whp);
  gemm_xproj_8p<<<4096,  512, 0, stream>>>(eb, WxT, bias, xpb);
  lstm_recur   <<<256,   256, 0, stream>>>(xpb, whp, hb, out, fl);
}